// Round 5
// baseline (418.308 us; speedup 1.0000x reference)
//
#include <hip/hip_runtime.h>
#include <math.h>

constexpr int NN   = 100000;
constexpr int NE   = 1600000;
constexpr int FIN  = 256;
constexpr int HID  = 64;
constexpr int FOUT = 40;
constexpr float SLOPE = 0.2f;
constexpr int NB    = (NN + 255) / 256;   // 391 buckets (256 nodes/bucket)
constexpr int NBUCK = NB;
constexpr int TILE_A = 2048;              // edges per partition-A workgroup
constexpr int NWG_A = (NE + TILE_A - 1) / TILE_A;  // 782
constexpr int AK = 264;                   // LDS row stride in bf16 (256 + 8 pad)

typedef short  short8  __attribute__((ext_vector_type(8)));
typedef float  floatx4 __attribute__((ext_vector_type(4)));

__device__ inline unsigned short f2bf(float x) {   // RNE fp32->bf16
    union { float f; unsigned int u; } c; c.f = x;
    unsigned int u = c.u;
    return (unsigned short)((u + 0x7FFF + ((u >> 16) & 1)) >> 16);
}

__device__ inline float readlane_f(float v, int l) {
    return __int_as_float(__builtin_amdgcn_readlane(__float_as_int(v), l));
}

// ---------------- W1^T bf16 prep + wl2/wr2 precompute -----------------------
// wl2 = W2 @ al2, wr2 = W2 @ ar2  (64-vectors) -- lets gather1 compute
// el2[d] = h[d].wl2 without materializing z2 = h@W2 per destination.
__global__ __launch_bounds__(256) void w1t_kernel(
    const float* __restrict__ W1, unsigned short* __restrict__ W1T,
    const float* __restrict__ W2, const float* __restrict__ al2,
    const float* __restrict__ ar2,
    float* __restrict__ wl2, float* __restrict__ wr2)
{
    int idx = blockIdx.x * 256 + threadIdx.x;       // 16384 elems
    if (idx < FIN * HID) {
        int k = idx >> 6, n = idx & 63;
        W1T[n * FIN + k] = f2bf(W1[idx]);
    }
    if (blockIdx.x == 0 && threadIdx.x < HID) {
        int k = threadIdx.x;
        float a = 0.f, b = 0.f;
        #pragma unroll 8
        for (int j = 0; j < FOUT; ++j) {
            float wv = W2[k * FOUT + j];
            a += wv * al2[j]; b += wv * ar2[j];
        }
        wl2[k] = a; wr2[k] = b;
    }
}

// ---------------- GEMM1 via bf16 MFMA: z = feat @ W1, fused el/er -----------
// A loaded DIRECTLY global->reg (coalesced 128B/row segments), converted to
// bf16 in registers. Only W1^T staged in LDS (~34 KB) -> 4 blocks/CU.
// Fused: LDS bucket histogram of dst>>8 merged into global bcnt[NBUCK].
// z stored as fp16 (halves gather-side traffic and footprint).
__global__ __launch_bounds__(256) void gemm1_kernel(
    const float* __restrict__ feat, const unsigned short* __restrict__ W1T,
    const float* __restrict__ al, const float* __restrict__ ar,
    const int* __restrict__ dst, int* __restrict__ bcnt,
    _Float16* __restrict__ z, float* __restrict__ el, float* __restrict__ er)
{
    __shared__ unsigned short sBT[64 * AK];   // W1^T bf16 [n][k]
    __shared__ int hist[NBUCK];
    const int t = threadIdx.x;
    const int ntile = blockIdx.x * 64;

    for (int i = t; i < NBUCK; i += 256) hist[i] = 0;
    // stage B^T: 2048 8-bf16 granules, 8 per thread
    #pragma unroll
    for (int i = 0; i < 8; ++i) {
        int g = t + 256 * i;
        int row = g >> 5, c8 = g & 31;
        *(uint4*)&sBT[row * AK + 8 * c8] = *(const uint4*)&W1T[row * FIN + 8 * c8];
    }
    __syncthreads();

    // bucket histogram: 1563 blocks * 256 thr * 4 edges == NE
    {
        int base = (blockIdx.x * 256 + t) * 4;
        if (base < NE) {  // NE % 4 == 0
            const int4 d4 = *(const int4*)&dst[base];
            atomicAdd(&hist[d4.x >> 8], 1); atomicAdd(&hist[d4.y >> 8], 1);
            atomicAdd(&hist[d4.z >> 8], 1); atomicAdd(&hist[d4.w >> 8], 1);
        }
    }
    __syncthreads();
    for (int i = t; i < NBUCK; i += 256) {
        int hv = hist[i];
        if (hv) atomicAdd(&bcnt[i], hv);
    }

    const int w  = t >> 6;        // wave id -> node rows m0..m0+15
    const int l  = t & 63;
    const int lr = l & 15;        // A row / B col / D col within tile
    const int q  = l >> 4;        // quad
    const int m0 = 16 * w;

    int n = ntile + m0 + lr; if (n >= NN) n = NN - 1;
    const float* __restrict__ arow = feat + (size_t)n * FIN;

    floatx4 acc[4];
    #pragma unroll
    for (int tile = 0; tile < 4; ++tile) acc[tile] = 0.f;

    #pragma unroll
    for (int kc = 0; kc < 8; ++kc) {
        const int koff = kc * 32 + 8 * q;
        const float4 fa = *(const float4*)(arow + koff);
        const float4 fb = *(const float4*)(arow + koff + 4);
        short8 av;
        av[0] = (short)f2bf(fa.x); av[1] = (short)f2bf(fa.y);
        av[2] = (short)f2bf(fa.z); av[3] = (short)f2bf(fa.w);
        av[4] = (short)f2bf(fb.x); av[5] = (short)f2bf(fb.y);
        av[6] = (short)f2bf(fb.z); av[7] = (short)f2bf(fb.w);
        #pragma unroll
        for (int tile = 0; tile < 4; ++tile) {
            const short8 bv = *(const short8*)(sBT + (16 * tile + lr) * AK + koff);
            acc[tile] = __builtin_amdgcn_mfma_f32_16x16x32_bf16(av, bv, acc[tile], 0, 0, 0);
        }
    }

    // epilogue: z store (fp16) + el/er (reduce over n within 16-lane groups)
    float aln[4], arn[4];
    #pragma unroll
    for (int tile = 0; tile < 4; ++tile) {
        aln[tile] = al[16 * tile + lr];
        arn[tile] = ar[16 * tile + lr];
    }
    #pragma unroll
    for (int r = 0; r < 4; ++r) {
        int mg = ntile + m0 + 4 * q + r;
        float pl = 0.f, pr = 0.f;
        #pragma unroll
        for (int tile = 0; tile < 4; ++tile) {
            float zv = acc[tile][r];
            pl += zv * aln[tile]; pr += zv * arn[tile];
        }
        #pragma unroll
        for (int off = 8; off >= 1; off >>= 1) {
            pl += __shfl_xor(pl, off);
            pr += __shfl_xor(pr, off);
        }
        if (mg < NN) {
            #pragma unroll
            for (int tile = 0; tile < 4; ++tile)
                z[(size_t)mg * HID + 16 * tile + lr] = (_Float16)acc[tile][r];
            if (lr == 0) { el[mg] = pl; er[mg] = pr; }
        }
    }
}

// ---------------- bucket scan (391 elems): bofs/gcur init -------------------
__global__ __launch_bounds__(512) void scan_top_kernel(
    const int* __restrict__ bcnt, int* __restrict__ bofs, int* __restrict__ gcur)
{
    __shared__ int tmp[512];
    int t = threadIdx.x;
    int v = (t < NB) ? bcnt[t] : 0;
    tmp[t] = v; __syncthreads();
    for (int off = 1; off < 512; off <<= 1) {
        int x = (t >= off) ? tmp[t - off] : 0;
        __syncthreads();
        tmp[t] += x;
        __syncthreads();
    }
    int excl = tmp[t] - v;
    if (t < NB) { bofs[t] = excl; gcur[t] = excl; }
    if (t == NB - 1) bofs[NB] = excl + v;  // == NE
}

// ---------------- Pass A: bucket partition (1024-thr blocks) ----------------
// pack = (src << 8) | (dst & 255); bucket = dst >> 8
__global__ __launch_bounds__(1024) void partitionA_kernel(
    const int* __restrict__ src, const int* __restrict__ dst,
    int* __restrict__ gcur, int* __restrict__ ebuck)
{
    __shared__ int hist[NBUCK];
    __shared__ int lcur[NBUCK];
    const int t = threadIdx.x;
    const int e0 = blockIdx.x * TILE_A;
    const int e1 = (e0 + TILE_A < NE) ? e0 + TILE_A : NE;

    for (int i = t; i < NBUCK; i += 1024) hist[i] = 0;
    __syncthreads();
    for (int e = e0 + t; e < e1; e += 1024)
        atomicAdd(&hist[dst[e] >> 8], 1);
    __syncthreads();
    for (int i = t; i < NBUCK; i += 1024) {
        int hv = hist[i];
        lcur[i] = hv ? atomicAdd(&gcur[i], hv) : 0;
    }
    __syncthreads();
    for (int e = e0 + t; e < e1; e += 1024) {
        int d = dst[e], s = src[e];
        int p = atomicAdd(&lcur[d >> 8], 1);
        ebuck[p] = (s << 8) | (d & 255);
    }
}

// ---------------- Pass B: per-bucket degree count + scan + CSR scatter ------
__global__ __launch_bounds__(1024) void partitionB_kernel(
    const int* __restrict__ bofs, const int* __restrict__ ebuck,
    int* __restrict__ row_ptr, int* __restrict__ esrc)
{
    __shared__ int sdeg[256];
    __shared__ int sscan[256];
    __shared__ int scur[256];
    const int b = blockIdx.x;
    const int n0 = b << 8;
    const int t = threadIdx.x;
    const int r0 = bofs[b], r1 = bofs[b + 1];

    if (t < 256) sdeg[t] = 0;
    __syncthreads();
    for (int e = r0 + t; e < r1; e += 1024)
        atomicAdd(&sdeg[ebuck[e] & 255], 1);
    __syncthreads();

    // inclusive Hillis-Steele scan over 256 degrees (threads 0..255)
    if (t < 256) sscan[t] = sdeg[t];
    __syncthreads();
    for (int off = 1; off < 256; off <<= 1) {
        int x = 0;
        if (t < 256 && t >= off) x = sscan[t - off];
        __syncthreads();
        if (t < 256) sscan[t] += x;
        __syncthreads();
    }
    if (t < 256) {
        int excl = sscan[t] - sdeg[t];
        if (n0 + t < NN) row_ptr[n0 + t] = r0 + excl;
        scur[t] = r0 + excl;
    }
    if (b == NBUCK - 1 && t == 0) row_ptr[NN] = NE;
    __syncthreads();

    for (int e = r0 + t; e < r1; e += 1024) {
        int pk = ebuck[e];
        int p = atomicAdd(&scur[pk & 255], 1);
        esrc[p] = pk >> 8;
    }
}

// ---------------- fused per-destination GAT gather (64-dim fp16 rows) -------
// Per-edge (weight, src) pairs are wave-uniform: broadcast via v_readlane into
// SGPRs so the z-row base address is SCALAR and the load is saddr+lane-offset.
// FIRST: aggregates z1, emits h = relu(res+b1) (fp16) and el2/er2 via the
//        precomputed wl2/wr2 vectors (2 FMA + butterfly -- no dense GEMM).
// !FIRST: aggregates h, emits raw aggregate hagg (fp32); W2/b2/log_softmax
//        applied by the streaming out_kernel afterwards.
template<bool FIRST>
__global__ __launch_bounds__(256) void gat_gather_kernel(
    const int* __restrict__ row_ptr, const int* __restrict__ esrc,
    const float* __restrict__ el, const float* __restrict__ er,
    const _Float16* __restrict__ zin, const float* __restrict__ b1,
    const float* __restrict__ wl2, const float* __restrict__ wr2,
    _Float16* __restrict__ hout, float* __restrict__ haggout,
    float* __restrict__ el2, float* __restrict__ er2)
{
    const int w = threadIdx.x >> 6, lane = threadIdx.x & 63;
    const int d = blockIdx.x * 4 + w;          // NN % 4 == 0
    const int r0 = row_ptr[d], r1 = row_ptr[d + 1];
    const int cnt = r1 - r0;
    const float erd = er[d];

    float accv = 0.f;
    float s = 0.f;

    if (cnt <= 64) {
        int sn = 0; float v = -INFINITY;
        if (lane < cnt) {
            sn = esrc[r0 + lane];
            v = el[sn] + erd;
            v = (v >= 0.f) ? v : SLOPE * v;
        }
        float m = v;
        #pragma unroll
        for (int off = 32; off >= 1; off >>= 1) m = fmaxf(m, __shfl_xor(m, off));
        float wv = (lane < cnt) ? __expf(v - m) : 0.f;
        s = wv;
        #pragma unroll
        for (int off = 32; off >= 1; off >>= 1) s += __shfl_xor(s, off);
        {
            int j = 0;
            for (; j + 8 <= cnt; j += 8) {
                float a0 = 0.f, a1 = 0.f;
                #pragma unroll
                for (int qq = 0; qq < 8; qq += 2) {
                    float w0 = readlane_f(wv, j + qq);
                    int   s0 = __builtin_amdgcn_readlane(sn, j + qq);
                    float w1 = readlane_f(wv, j + qq + 1);
                    int   s1 = __builtin_amdgcn_readlane(sn, j + qq + 1);
                    a0 += w0 * (float)zin[(size_t)s0 * HID + lane];
                    a1 += w1 * (float)zin[(size_t)s1 * HID + lane];
                }
                accv += a0 + a1;
            }
            for (; j < cnt; ++j) {
                float w0 = readlane_f(wv, j);
                int   s0 = __builtin_amdgcn_readlane(sn, j);
                accv += w0 * (float)zin[(size_t)s0 * HID + lane];
            }
        }
    } else {
        float m = -INFINITY;
        for (int e = r0 + lane; e < r1; e += 64) {
            float v = el[esrc[e]] + erd;
            v = (v >= 0.f) ? v : SLOPE * v;
            m = fmaxf(m, v);
        }
        #pragma unroll
        for (int off = 32; off >= 1; off >>= 1) m = fmaxf(m, __shfl_xor(m, off));
        for (int base = r0; base < r1; base += 64) {
            int e = base + lane;
            float wv = 0.f; int sn = 0;
            if (e < r1) {
                sn = esrc[e];
                float v = el[sn] + erd;
                v = (v >= 0.f) ? v : SLOPE * v;
                wv = __expf(v - m);
            }
            s += wv;
            int c = r1 - base; if (c > 64) c = 64;
            {
                int j = 0;
                for (; j + 4 <= c; j += 4) {
                    float a0 = 0.f, a1 = 0.f;
                    #pragma unroll
                    for (int qq = 0; qq < 4; qq += 2) {
                        float w0 = readlane_f(wv, j + qq);
                        int   s0 = __builtin_amdgcn_readlane(sn, j + qq);
                        float w1 = readlane_f(wv, j + qq + 1);
                        int   s1 = __builtin_amdgcn_readlane(sn, j + qq + 1);
                        a0 += w0 * (float)zin[(size_t)s0 * HID + lane];
                        a1 += w1 * (float)zin[(size_t)s1 * HID + lane];
                    }
                    accv += a0 + a1;
                }
                for (; j < c; ++j) {
                    float w0 = readlane_f(wv, j);
                    int   s0 = __builtin_amdgcn_readlane(sn, j);
                    accv += w0 * (float)zin[(size_t)s0 * HID + lane];
                }
            }
        }
        #pragma unroll
        for (int off = 32; off >= 1; off >>= 1) s += __shfl_xor(s, off);
    }

    float res = (cnt > 0) ? (accv / s) : 0.f;

    if (FIRST) {
        float hval = res + b1[lane];
        hval = (hval > 0.f) ? hval : 0.f;
        hout[(size_t)d * HID + lane] = (_Float16)hval;
        float pl = hval * wl2[lane];
        float pr = hval * wr2[lane];
        #pragma unroll
        for (int off = 32; off >= 1; off >>= 1) {
            pl += __shfl_xor(pl, off); pr += __shfl_xor(pr, off);
        }
        if (lane == 0) { el2[d] = pl; er2[d] = pr; }
    } else {
        haggout[(size_t)d * HID + lane] = res;
    }
}

// ---------------- final: out = log_softmax(hagg @ W2 + b2) ------------------
__global__ __launch_bounds__(256) void out_kernel(
    const float* __restrict__ hagg, const float* __restrict__ W2,
    const float* __restrict__ b2, float* __restrict__ out)
{
    __shared__ float sh[4][64];
    const int w = threadIdx.x >> 6, lane = threadIdx.x & 63;
    const int n = blockIdx.x * 4 + w;          // NN % 4 == 0
    sh[w][lane] = hagg[(size_t)n * HID + lane];
    __syncthreads();
    float acc = 0.f;
    if (lane < FOUT) {
        #pragma unroll 8
        for (int k = 0; k < HID; ++k) acc += sh[w][k] * W2[k * FOUT + lane];
    }
    float v = (lane < FOUT) ? acc + b2[lane] : -INFINITY;
    float mx = v;
    #pragma unroll
    for (int off = 32; off >= 1; off >>= 1) mx = fmaxf(mx, __shfl_xor(mx, off));
    float ex = (lane < FOUT) ? __expf(v - mx) : 0.f;
    float sm = ex;
    #pragma unroll
    for (int off = 32; off >= 1; off >>= 1) sm += __shfl_xor(sm, off);
    if (lane < FOUT) out[(size_t)n * FOUT + lane] = v - mx - __logf(sm);
}

extern "C" void kernel_launch(void* const* d_in, const int* in_sizes, int n_in,
                              void* d_out, int out_size, void* d_ws, size_t ws_size,
                              hipStream_t stream) {
    const float* feat = (const float*)d_in[0];
    const int*   src  = (const int*)d_in[1];
    const int*   dst  = (const int*)d_in[2];
    const float* W1   = (const float*)d_in[3];
    const float* b1   = (const float*)d_in[4];
    const float* al1  = (const float*)d_in[5];
    const float* ar1  = (const float*)d_in[6];
    const float* W2   = (const float*)d_in[7];
    const float* b2   = (const float*)d_in[8];
    const float* al2  = (const float*)d_in[9];
    const float* ar2  = (const float*)d_in[10];
    float* out = (float*)d_out;

    char* p = (char*)d_ws;
    // hagg (fp32, 25.6 MB) aliases z1 (fp16, first 12.8 MB): z1 dead after
    // gather1; hagg written by gather2 (strictly later). Keeps footprint
    // within the proven workspace size.
    float*    hagg = (float*)p;
    _Float16* z1   = (_Float16*)p;  p += (size_t)NN * HID * 4;  // 25.6 MB
    _Float16* h    = (_Float16*)p;  p += (size_t)NN * HID * 2;  // 12.8 MB
    float* el1   = (float*)p;     p += (size_t)NN * 4;
    float* er1   = (float*)p;     p += (size_t)NN * 4;
    float* el2   = (float*)p;     p += (size_t)NN * 4;
    float* er2   = (float*)p;     p += (size_t)NN * 4;
    float* wl2   = (float*)p;     p += HID * 4;
    float* wr2   = (float*)p;     p += HID * 4;
    int*   bcnt  = (int*)p;       p += NB * 4;
    int*   bofs  = (int*)p;       p += (NB + 1) * 4;
    int*   gcur  = (int*)p;       p += NBUCK * 4;
    int*   rowp  = (int*)p;       p += (NN + 1) * 4;
    int*   esrc  = (int*)p;       p += (size_t)NE * 4;          // 6.4 MB
    int*   ebuck = (int*)p;       p += (size_t)NE * 4;          // 6.4 MB
    unsigned short* w1t = (unsigned short*)p;                   // FIN*HID bf16

    hipMemsetAsync(bcnt, 0, NB * sizeof(int), stream);

    // ---- W1^T bf16 + wl2/wr2 prep, layer-1 MFMA GEMM + bucket histogram ----
    w1t_kernel<<<(FIN * HID + 255) / 256, 256, 0, stream>>>(
        W1, w1t, W2, al2, ar2, wl2, wr2);
    gemm1_kernel<<<(NN + 63) / 64, 256, 0, stream>>>(feat, w1t, al1, ar1, dst, bcnt, z1, el1, er1);

    // ---- CSR build (bucket scan -> partition -> per-bucket scan/scatter) ----
    scan_top_kernel<<<1, 512, 0, stream>>>(bcnt, bofs, gcur);
    partitionA_kernel<<<NWG_A, 1024, 0, stream>>>(src, dst, gcur, ebuck);
    partitionB_kernel<<<NBUCK, 1024, 0, stream>>>(bofs, ebuck, rowp, esrc);

    // ---- layer-1 gather: h + el2/er2 (via wl2/wr2); no dense GEMM in-loop --
    gat_gather_kernel<true><<<NN / 4, 256, 0, stream>>>(
        rowp, esrc, el1, er1, z1, b1, wl2, wr2, h, nullptr, el2, er2);

    // ---- layer-2 gather: aggregate h -> hagg (W2 deferred) ----
    gat_gather_kernel<false><<<NN / 4, 256, 0, stream>>>(
        rowp, esrc, el2, er2, h, nullptr, nullptr, nullptr,
        nullptr, hagg, nullptr, nullptr);

    // ---- final: out = log_softmax(hagg @ W2 + b2) (streaming, coalesced) ---
    out_kernel<<<NN / 4, 256, 0, stream>>>(hagg, W2, b2, out);
}

// Round 7
// 410.694 us; speedup vs baseline: 1.0185x; 1.0185x over previous
//
#include <hip/hip_runtime.h>
#include <math.h>

constexpr int NN   = 100000;
constexpr int NE   = 1600000;
constexpr int FIN  = 256;
constexpr int HID  = 64;
constexpr int FOUT = 40;
constexpr float SLOPE = 0.2f;
constexpr int NBUCK = (NN + 127) / 128;   // 782 buckets (128 nodes/bucket)
constexpr int TILE_A = 2048;              // edges per partition-A block
constexpr int NWG_A = (NE + TILE_A - 1) / TILE_A;  // 782
constexpr int NT_GEMM = (NN + 63) / 64;   // 1563 gemm tiles
constexpr int AK = 264;                   // LDS row stride in bf16 (256 + 8 pad)
constexpr int HB = 64;                    // w1t blocks in prep
constexpr int HIST_EPB = 4096;            // edges per hist block in prep
constexpr int NWG_H = (NE + HIST_EPB - 1) / HIST_EPB;  // 391

typedef short  short8  __attribute__((ext_vector_type(8)));
typedef float  floatx4 __attribute__((ext_vector_type(4)));

__device__ inline unsigned short f2bf(float x) {   // RNE fp32->bf16
    union { float f; unsigned int u; } c; c.f = x;
    unsigned int u = c.u;
    return (unsigned short)((u + 0x7FFF + ((u >> 16) & 1)) >> 16);
}

__device__ inline float readlane_f(float v, int l) {
    return __int_as_float(__builtin_amdgcn_readlane(__float_as_int(v), l));
}

// Local exclusive scan of bcnt[NBUCK] into LDS bofs[NBUCK+1].
// 256 threads, 4 elems/thread (NBUCK=782 <= 1024). All threads must call.
__device__ inline void scan_buckets(const int* __restrict__ gcnt,
                                    int* __restrict__ bofs,
                                    int* __restrict__ tsum, int t)
{
    int i0 = 4 * t;
    int c0 = (i0 + 0 < NBUCK) ? gcnt[i0 + 0] : 0;
    int c1 = (i0 + 1 < NBUCK) ? gcnt[i0 + 1] : 0;
    int c2 = (i0 + 2 < NBUCK) ? gcnt[i0 + 2] : 0;
    int c3 = (i0 + 3 < NBUCK) ? gcnt[i0 + 3] : 0;
    int s = c0 + c1 + c2 + c3;
    tsum[t] = s;
    __syncthreads();
    for (int off = 1; off < 256; off <<= 1) {
        int x = (t >= off) ? tsum[t - off] : 0;
        __syncthreads();
        tsum[t] += x;
        __syncthreads();
    }
    int e0 = tsum[t] - s;
    if (i0 + 0 <= NBUCK) bofs[i0 + 0] = e0;
    if (i0 + 1 <= NBUCK) bofs[i0 + 1] = e0 + c0;
    if (i0 + 2 <= NBUCK) bofs[i0 + 2] = e0 + c0 + c1;
    if (i0 + 3 <= NBUCK) bofs[i0 + 3] = e0 + c0 + c1 + c2;
    __syncthreads();
}

// ---------------- prep: W1^T bf16, wl2/wr2, dst bucket histogram ------------
__global__ __launch_bounds__(256) void prep_kernel(
    const float* __restrict__ W1, unsigned short* __restrict__ W1T,
    const float* __restrict__ W2, const float* __restrict__ al2,
    const float* __restrict__ ar2,
    float* __restrict__ wl2, float* __restrict__ wr2,
    const int* __restrict__ dst, int* __restrict__ bcnt)
{
    const int t = threadIdx.x;
    if (blockIdx.x < HB) {
        int idx = blockIdx.x * 256 + t;          // 16384 elems
        if (idx < FIN * HID) {
            int k = idx >> 6, n = idx & 63;
            W1T[n * FIN + k] = f2bf(W1[idx]);
        }
        if (blockIdx.x == 0 && t < HID) {
            int k = t;
            float a = 0.f, b = 0.f;
            #pragma unroll 8
            for (int j = 0; j < FOUT; ++j) {
                float wv = W2[k * FOUT + j];
                a += wv * al2[j]; b += wv * ar2[j];
            }
            wl2[k] = a; wr2[k] = b;
        }
    } else {
        __shared__ int hist[NBUCK];
        for (int i = t; i < NBUCK; i += 256) hist[i] = 0;
        __syncthreads();
        int base = (blockIdx.x - HB) * HIST_EPB + t * 16;
        #pragma unroll
        for (int k = 0; k < 4; ++k) {
            int idx = base + 4 * k;
            if (idx < NE) {     // NE % 4 == 0
                const int4 d4 = *(const int4*)&dst[idx];
                atomicAdd(&hist[d4.x >> 7], 1); atomicAdd(&hist[d4.y >> 7], 1);
                atomicAdd(&hist[d4.z >> 7], 1); atomicAdd(&hist[d4.w >> 7], 1);
            }
        }
        __syncthreads();
        for (int i = t; i < NBUCK; i += 256) {
            int hv = hist[i];
            if (hv) atomicAdd(&bcnt[i], hv);
        }
    }
}

// ---------------- MEGA: gemm1 tiles (blocks < NT_GEMM) || partitionA --------
// gemm1: z = feat @ W1 via bf16 MFMA, fused el/er. A direct global->reg,
// W1^T staged in LDS. partA: bucket partition with LOCAL scan of bcnt
// (no scan_top dispatch); slot claim via cur0 (memset 0) + local bofs.
__global__ __launch_bounds__(256) void mega_kernel(
    const float* __restrict__ feat, const unsigned short* __restrict__ W1T,
    const float* __restrict__ al, const float* __restrict__ ar,
    const int* __restrict__ src, const int* __restrict__ dst,
    const int* __restrict__ bcnt, int* __restrict__ cur0,
    int* __restrict__ ebuck,
    _Float16* __restrict__ z, float* __restrict__ el, float* __restrict__ er)
{
    __shared__ int smem4[8448];   // 33.8 KB: sBT (gemm) | hist/bofs/tsum/lcur (partA)
    const int t = threadIdx.x;

    if (blockIdx.x < NT_GEMM) {
        unsigned short* sBT = (unsigned short*)smem4;   // W1^T bf16 [n][k], stride AK
        const int ntile = blockIdx.x * 64;

        #pragma unroll
        for (int i = 0; i < 8; ++i) {
            int g = t + 256 * i;
            int row = g >> 5, c8 = g & 31;
            *(uint4*)&sBT[row * AK + 8 * c8] = *(const uint4*)&W1T[row * FIN + 8 * c8];
        }
        __syncthreads();

        const int w  = t >> 6;
        const int l  = t & 63;
        const int lr = l & 15;
        const int q  = l >> 4;
        const int m0 = 16 * w;

        int n = ntile + m0 + lr; if (n >= NN) n = NN - 1;
        const float* __restrict__ arow = feat + (size_t)n * FIN;

        floatx4 acc[4];
        #pragma unroll
        for (int tile = 0; tile < 4; ++tile) acc[tile] = 0.f;

        #pragma unroll
        for (int kc = 0; kc < 8; ++kc) {
            const int koff = kc * 32 + 8 * q;
            const float4 fa = *(const float4*)(arow + koff);
            const float4 fb = *(const float4*)(arow + koff + 4);
            short8 av;
            av[0] = (short)f2bf(fa.x); av[1] = (short)f2bf(fa.y);
            av[2] = (short)f2bf(fa.z); av[3] = (short)f2bf(fa.w);
            av[4] = (short)f2bf(fb.x); av[5] = (short)f2bf(fb.y);
            av[6] = (short)f2bf(fb.z); av[7] = (short)f2bf(fb.w);
            #pragma unroll
            for (int tile = 0; tile < 4; ++tile) {
                const short8 bv = *(const short8*)(sBT + (16 * tile + lr) * AK + koff);
                acc[tile] = __builtin_amdgcn_mfma_f32_16x16x32_bf16(av, bv, acc[tile], 0, 0, 0);
            }
        }

        float aln[4], arn[4];
        #pragma unroll
        for (int tile = 0; tile < 4; ++tile) {
            aln[tile] = al[16 * tile + lr];
            arn[tile] = ar[16 * tile + lr];
        }
        #pragma unroll
        for (int r = 0; r < 4; ++r) {
            int mg = ntile + m0 + 4 * q + r;
            float pl = 0.f, pr = 0.f;
            #pragma unroll
            for (int tile = 0; tile < 4; ++tile) {
                float zv = acc[tile][r];
                pl += zv * aln[tile]; pr += zv * arn[tile];
            }
            #pragma unroll
            for (int off = 8; off >= 1; off >>= 1) {
                pl += __shfl_xor(pl, off);
                pr += __shfl_xor(pr, off);
            }
            if (mg < NN) {
                #pragma unroll
                for (int tile = 0; tile < 4; ++tile)
                    z[(size_t)mg * HID + 16 * tile + lr] = (_Float16)acc[tile][r];
                if (lr == 0) { el[mg] = pl; er[mg] = pr; }
            }
        }
    } else {
        // ---- partitionA: pack = (src << 7) | (dst & 127); bucket = dst >> 7
        int* hist = smem4;                       // [NBUCK]
        int* bofs = smem4 + NBUCK;               // [NBUCK+1]
        int* tsum = smem4 + 2 * NBUCK + 1;       // [256]
        int* lcur = smem4 + 2 * NBUCK + 1 + 256; // [NBUCK]
        const int blk = blockIdx.x - NT_GEMM;
        const int e0 = blk * TILE_A;
        const int e1 = (e0 + TILE_A < NE) ? e0 + TILE_A : NE;

        for (int i = t; i < NBUCK; i += 256) hist[i] = 0;
        scan_buckets(bcnt, bofs, tsum, t);       // first barrier covers hist zeroing
        for (int e = e0 + t; e < e1; e += 256)
            atomicAdd(&hist[dst[e] >> 7], 1);
        __syncthreads();
        for (int i = t; i < NBUCK; i += 256) {
            int hv = hist[i];
            if (hv) lcur[i] = bofs[i] + atomicAdd(&cur0[i], hv);
        }
        __syncthreads();
        for (int e = e0 + t; e < e1; e += 256) {
            int d = dst[e], s_ = src[e];
            int p = atomicAdd(&lcur[d >> 7], 1);
            ebuck[p] = (s_ << 7) | (d & 127);
        }
    }
}

// ---------------- partB: per-bucket degree count + scan + CSR scatter -------
// 782 blocks (1 per 128-node bucket), local bucket scan from bcnt.
__global__ __launch_bounds__(256) void partB_kernel(
    const int* __restrict__ bcnt, const int* __restrict__ ebuck,
    int* __restrict__ row_ptr, int* __restrict__ esrc)
{
    __shared__ int bofs[NBUCK + 1];
    __shared__ int tsum[256];
    __shared__ int sdeg[128];
    __shared__ int sscan[128];
    __shared__ int scur[128];
    const int b = blockIdx.x;
    const int n0 = b << 7;
    const int t = threadIdx.x;

    if (t < 128) sdeg[t] = 0;
    scan_buckets(bcnt, bofs, tsum, t);           // first barrier covers sdeg zeroing
    const int r0 = bofs[b], r1 = bofs[b + 1];

    for (int e = r0 + t; e < r1; e += 256)
        atomicAdd(&sdeg[ebuck[e] & 127], 1);
    __syncthreads();

    if (t < 128) sscan[t] = sdeg[t];
    __syncthreads();
    for (int off = 1; off < 128; off <<= 1) {
        int x = (t < 128 && t >= off) ? sscan[t - off] : 0;
        __syncthreads();
        if (t < 128) sscan[t] += x;
        __syncthreads();
    }
    if (t < 128) {
        int excl = sscan[t] - sdeg[t];
        if (n0 + t < NN) row_ptr[n0 + t] = r0 + excl;
        scur[t] = r0 + excl;
    }
    if (b == NBUCK - 1 && t == 0) row_ptr[NN] = NE;
    __syncthreads();

    for (int e = r0 + t; e < r1; e += 256) {
        int pk = ebuck[e];
        int p = atomicAdd(&scur[pk & 127], 1);
        esrc[p] = pk >> 7;
    }
}

// ---------------- fused per-destination GAT gather (64-dim fp16 rows) -------
// Per-edge (weight, src) pairs are wave-uniform: broadcast via v_readlane into
// SGPRs so the z-row base address is SCALAR and the load is saddr+lane-offset.
// FIRST: aggregates z1, emits h = relu(res+b1) (fp16) and el2/er2 via wl2/wr2.
// !FIRST: aggregates h, emits raw aggregate hagg (fp32); W2 deferred.
template<bool FIRST>
__global__ __launch_bounds__(256) void gat_gather_kernel(
    const int* __restrict__ row_ptr, const int* __restrict__ esrc,
    const float* __restrict__ el, const float* __restrict__ er,
    const _Float16* __restrict__ zin, const float* __restrict__ b1,
    const float* __restrict__ wl2, const float* __restrict__ wr2,
    _Float16* __restrict__ hout, float* __restrict__ haggout,
    float* __restrict__ el2, float* __restrict__ er2)
{
    const int w = threadIdx.x >> 6, lane = threadIdx.x & 63;
    const int d = blockIdx.x * 4 + w;          // NN % 4 == 0
    const int r0 = row_ptr[d], r1 = row_ptr[d + 1];
    const int cnt = r1 - r0;
    const float erd = er[d];

    float accv = 0.f;
    float s = 0.f;

    if (cnt <= 64) {
        int sn = 0; float v = -INFINITY;
        if (lane < cnt) {
            sn = esrc[r0 + lane];
            v = el[sn] + erd;
            v = (v >= 0.f) ? v : SLOPE * v;
        }
        float m = v;
        #pragma unroll
        for (int off = 32; off >= 1; off >>= 1) m = fmaxf(m, __shfl_xor(m, off));
        float wv = (lane < cnt) ? __expf(v - m) : 0.f;
        s = wv;
        #pragma unroll
        for (int off = 32; off >= 1; off >>= 1) s += __shfl_xor(s, off);
        {
            int j = 0;
            for (; j + 8 <= cnt; j += 8) {
                float a0 = 0.f, a1 = 0.f;
                #pragma unroll
                for (int qq = 0; qq < 8; qq += 2) {
                    float w0 = readlane_f(wv, j + qq);
                    int   s0 = __builtin_amdgcn_readlane(sn, j + qq);
                    float w1 = readlane_f(wv, j + qq + 1);
                    int   s1 = __builtin_amdgcn_readlane(sn, j + qq + 1);
                    a0 += w0 * (float)zin[(size_t)s0 * HID + lane];
                    a1 += w1 * (float)zin[(size_t)s1 * HID + lane];
                }
                accv += a0 + a1;
            }
            for (; j < cnt; ++j) {
                float w0 = readlane_f(wv, j);
                int   s0 = __builtin_amdgcn_readlane(sn, j);
                accv += w0 * (float)zin[(size_t)s0 * HID + lane];
            }
        }
    } else {
        float m = -INFINITY;
        for (int e = r0 + lane; e < r1; e += 64) {
            float v = el[esrc[e]] + erd;
            v = (v >= 0.f) ? v : SLOPE * v;
            m = fmaxf(m, v);
        }
        #pragma unroll
        for (int off = 32; off >= 1; off >>= 1) m = fmaxf(m, __shfl_xor(m, off));
        for (int base = r0; base < r1; base += 64) {
            int e = base + lane;
            float wv = 0.f; int sn = 0;
            if (e < r1) {
                sn = esrc[e];
                float v = el[sn] + erd;
                v = (v >= 0.f) ? v : SLOPE * v;
                wv = __expf(v - m);
            }
            s += wv;
            int c = r1 - base; if (c > 64) c = 64;
            {
                int j = 0;
                for (; j + 4 <= c; j += 4) {
                    float a0 = 0.f, a1 = 0.f;
                    #pragma unroll
                    for (int qq = 0; qq < 4; qq += 2) {
                        float w0 = readlane_f(wv, j + qq);
                        int   s0 = __builtin_amdgcn_readlane(sn, j + qq);
                        float w1 = readlane_f(wv, j + qq + 1);
                        int   s1 = __builtin_amdgcn_readlane(sn, j + qq + 1);
                        a0 += w0 * (float)zin[(size_t)s0 * HID + lane];
                        a1 += w1 * (float)zin[(size_t)s1 * HID + lane];
                    }
                    accv += a0 + a1;
                }
                for (; j < c; ++j) {
                    float w0 = readlane_f(wv, j);
                    int   s0 = __builtin_amdgcn_readlane(sn, j);
                    accv += w0 * (float)zin[(size_t)s0 * HID + lane];
                }
            }
        }
        #pragma unroll
        for (int off = 32; off >= 1; off >>= 1) s += __shfl_xor(s, off);
    }

    float res = (cnt > 0) ? (accv / s) : 0.f;

    if (FIRST) {
        float hval = res + b1[lane];
        hval = (hval > 0.f) ? hval : 0.f;
        hout[(size_t)d * HID + lane] = (_Float16)hval;
        float pl = hval * wl2[lane];
        float pr = hval * wr2[lane];
        #pragma unroll
        for (int off = 32; off >= 1; off >>= 1) {
            pl += __shfl_xor(pl, off); pr += __shfl_xor(pr, off);
        }
        if (lane == 0) { el2[d] = pl; er2[d] = pr; }
    } else {
        haggout[(size_t)d * HID + lane] = res;
    }
}

// ---------------- final: out = log_softmax(hagg @ W2 + b2) ------------------
__global__ __launch_bounds__(256) void out_kernel(
    const float* __restrict__ hagg, const float* __restrict__ W2,
    const float* __restrict__ b2, float* __restrict__ out)
{
    __shared__ float sh[4][64];
    const int w = threadIdx.x >> 6, lane = threadIdx.x & 63;
    const int n = blockIdx.x * 4 + w;          // NN % 4 == 0
    sh[w][lane] = hagg[(size_t)n * HID + lane];
    __syncthreads();
    float acc = 0.f;
    if (lane < FOUT) {
        #pragma unroll 8
        for (int k = 0; k < HID; ++k) acc += sh[w][k] * W2[k * FOUT + lane];
    }
    float v = (lane < FOUT) ? acc + b2[lane] : -INFINITY;
    float mx = v;
    #pragma unroll
    for (int off = 32; off >= 1; off >>= 1) mx = fmaxf(mx, __shfl_xor(mx, off));
    float ex = (lane < FOUT) ? __expf(v - mx) : 0.f;
    float sm = ex;
    #pragma unroll
    for (int off = 32; off >= 1; off >>= 1) sm += __shfl_xor(sm, off);
    if (lane < FOUT) out[(size_t)n * FOUT + lane] = v - mx - __logf(sm);
}

extern "C" void kernel_launch(void* const* d_in, const int* in_sizes, int n_in,
                              void* d_out, int out_size, void* d_ws, size_t ws_size,
                              hipStream_t stream) {
    const float* feat = (const float*)d_in[0];
    const int*   src  = (const int*)d_in[1];
    const int*   dst  = (const int*)d_in[2];
    const float* W1   = (const float*)d_in[3];
    const float* b1   = (const float*)d_in[4];
    const float* al1  = (const float*)d_in[5];
    const float* ar1  = (const float*)d_in[6];
    const float* W2   = (const float*)d_in[7];
    const float* b2   = (const float*)d_in[8];
    const float* al2  = (const float*)d_in[9];
    const float* ar2  = (const float*)d_in[10];
    float* out = (float*)d_out;

    char* p = (char*)d_ws;
    // hagg (fp32, 25.6 MB) aliases z1 (fp16, first 12.8 MB): z1 dead after
    // gather1; hagg written by gather2 (strictly later).
    float*    hagg = (float*)p;
    _Float16* z1   = (_Float16*)p;  p += (size_t)NN * HID * 4;  // 25.6 MB
    _Float16* h    = (_Float16*)p;  p += (size_t)NN * HID * 2;  // 12.8 MB
    float* el1   = (float*)p;     p += (size_t)NN * 4;
    float* er1   = (float*)p;     p += (size_t)NN * 4;
    float* el2   = (float*)p;     p += (size_t)NN * 4;
    float* er2   = (float*)p;     p += (size_t)NN * 4;
    float* wl2   = (float*)p;     p += HID * 4;
    float* wr2   = (float*)p;     p += HID * 4;
    int*   bcnt  = (int*)p;       p += NBUCK * 4;
    int*   cur0  = (int*)p;       p += NBUCK * 4;               // adjacent to bcnt
    int*   rowp  = (int*)p;       p += (NN + 1) * 4;
    int*   esrc  = (int*)p;       p += (size_t)NE * 4;          // 6.4 MB
    int*   ebuck = (int*)p;       p += (size_t)NE * 4;          // 6.4 MB
    unsigned short* w1t = (unsigned short*)p;                   // FIN*HID bf16

    hipMemsetAsync(bcnt, 0, 2 * NBUCK * sizeof(int), stream);   // bcnt + cur0

    // ---- prep: W1^T bf16 + wl2/wr2 + dst bucket histogram ----
    prep_kernel<<<HB + NWG_H, 256, 0, stream>>>(
        W1, w1t, W2, al2, ar2, wl2, wr2, dst, bcnt);

    // ---- MEGA: gemm1 (blocks 0..1562) || partitionA (blocks 1563..2344) ----
    mega_kernel<<<NT_GEMM + NWG_A, 256, 0, stream>>>(
        feat, w1t, al1, ar1, src, dst, bcnt, cur0, ebuck, z1, el1, er1);

    // ---- partB: per-bucket CSR finalize (local scan; no scan_top) ----
    partB_kernel<<<NBUCK, 256, 0, stream>>>(bcnt, ebuck, rowp, esrc);

    // ---- layer-1 gather: h + el2/er2 (via wl2/wr2) ----
    gat_gather_kernel<true><<<NN / 4, 256, 0, stream>>>(
        rowp, esrc, el1, er1, z1, b1, wl2, wr2, h, nullptr, el2, er2);

    // ---- layer-2 gather: aggregate h -> hagg (W2 deferred) ----
    gat_gather_kernel<false><<<NN / 4, 256, 0, stream>>>(
        rowp, esrc, el2, er2, h, nullptr, nullptr, nullptr,
        nullptr, hagg, nullptr, nullptr);

    // ---- final: out = log_softmax(hagg @ W2 + b2) ----
    out_kernel<<<NN / 4, 256, 0, stream>>>(hagg, W2, b2, out);
}